// Round 1
// baseline (6629.968 us; speedup 1.0000x reference)
//
#include <hip/hip_runtime.h>
#include <cmath>

#define B_  16
#define S_  512
#define D_  512
#define F_  2048
#define L_  6
#define MT  8192  // B_*S_ rows

// ------------------------------------------------------------- embed + PE
__global__ void embed_pe_kernel(const int* __restrict__ x,
                                const int* __restrict__ blen,
                                const float* __restrict__ emb,
                                float* __restrict__ h) {
  int bs = blockIdx.x;          // [0, B*S)
  int b = bs >> 9, s = bs & 511;
  int tok = x[bs];
  bool pe = s < blen[b];
  const float* er = emb + (long)tok * D_;
  float* hr = h + (long)bs * D_;
  for (int d = threadIdx.x; d < D_; d += 256) {
    float e = er[d];
    if (pe) {
      float ex = (2.0f * (float)d) / 512.0f;       // full-index exponent, exact in f32
      float ang = (float)s / powf(10000.0f, ex);
      e += (d & 1) ? cosf(ang) : sinf(ang);
    }
    hr[d] = e;
  }
}

// ------------------------------------------------------------- fp32 GEMM
// C[M,N] = A[M,K] @ W[K,N] (+bias) (+relu). BM=BN=128, BK=16, 256 thr, 8x8/thr.
#define BM 128
#define BN 128
#define BK 16
#define WST 132   // Ws row stride (pad): read banks (4k+8tx)%32, write 16B-aligned

__global__ __launch_bounds__(256, 2)
void gemm_kernel(const float* __restrict__ A, const float* __restrict__ W,
                 const float* __restrict__ bias, float* __restrict__ C,
                 int M, int N, int K, int relu) {
  __shared__ float As[BK][BM];     // stored transposed: As[k][m]
  __shared__ float Ws[BK][WST];
  int t = threadIdx.x;
  int rbase = blockIdx.y * BM;
  int cbase = blockIdx.x * BN;
  int ty = t >> 4, tx = t & 15;

  float acc[8][8];
#pragma unroll
  for (int i = 0; i < 8; i++)
#pragma unroll
    for (int j = 0; j < 8; j++) acc[i][j] = 0.0f;

  int arow = t >> 1;             // 0..127
  int acol = (t & 1) * 8;        // 0 or 8
  int wrow = t >> 4;             // 0..15
  int wcol = (t & 15) * 8;       // 0..120
  const float* Ap = A + (long)(rbase + arow) * K + acol;
  const float* Wp = W + (long)wrow * N + cbase + wcol;

  for (int kt = 0; kt < K; kt += BK) {
    // issue global loads early (overlap with previous tile's compute)
    float4 a0 = *(const float4*)(Ap + kt);
    float4 a1 = *(const float4*)(Ap + kt + 4);
    float4 w0 = *(const float4*)(Wp + (long)kt * N);
    float4 w1 = *(const float4*)(Wp + (long)kt * N + 4);
    __syncthreads();   // previous compute done reading LDS
    As[acol + 0][arow] = a0.x; As[acol + 1][arow] = a0.y;
    As[acol + 2][arow] = a0.z; As[acol + 3][arow] = a0.w;
    As[acol + 4][arow] = a1.x; As[acol + 5][arow] = a1.y;
    As[acol + 6][arow] = a1.z; As[acol + 7][arow] = a1.w;
    *(float4*)&Ws[wrow][wcol]     = w0;
    *(float4*)&Ws[wrow][wcol + 4] = w1;
    __syncthreads();
#pragma unroll
    for (int kk = 0; kk < BK; kk++) {
      float4 av0 = *(const float4*)&As[kk][ty * 8];
      float4 av1 = *(const float4*)&As[kk][ty * 8 + 4];
      float4 wv0 = *(const float4*)&Ws[kk][tx * 8];
      float4 wv1 = *(const float4*)&Ws[kk][tx * 8 + 4];
      float a[8] = {av0.x, av0.y, av0.z, av0.w, av1.x, av1.y, av1.z, av1.w};
      float b[8] = {wv0.x, wv0.y, wv0.z, wv0.w, wv1.x, wv1.y, wv1.z, wv1.w};
#pragma unroll
      for (int i = 0; i < 8; i++)
#pragma unroll
        for (int j = 0; j < 8; j++) acc[i][j] = fmaf(a[i], b[j], acc[i][j]);
    }
  }

#pragma unroll
  for (int i = 0; i < 8; i++) {
    long row = rbase + ty * 8 + i;
    int col = cbase + tx * 8;
    float o[8];
#pragma unroll
    for (int j = 0; j < 8; j++) {
      float v = acc[i][j];
      if (bias) v += bias[col + j];
      if (relu) v = fmaxf(v, 0.0f);
      o[j] = v;
    }
    *(float4*)(C + row * N + col)     = make_float4(o[0], o[1], o[2], o[3]);
    *(float4*)(C + row * N + col + 4) = make_float4(o[4], o[5], o[6], o[7]);
  }
}

// ------------------------------------------------------------- attention
// One WG = (block bh, q-tile of 32 rows). Faithful reshape: block bh is the
// contiguous [512,64] slice at offset bh*32768. Mask batch = bh % 16.
__global__ __launch_bounds__(256, 1)
void attn_kernel(const float* __restrict__ q, const float* __restrict__ k,
                 const float* __restrict__ v, const int* __restrict__ x,
                 float* __restrict__ ctx) {
  __shared__ float Qs[32][64];        // reads are 4-address broadcast -> no pad
  __shared__ float Ks[64][65];        // scalar reads, 65 -> <=2-way banks
  __shared__ float Vs[64][68];        // float4 reads, 16B-aligned rows
  __shared__ float Sb[32][521];       // logits, 521 -> <=2-way banks
  __shared__ float rowsum[32];
  __shared__ float smask[512];        // 1.0 where masked

  int bh = blockIdx.y;                // 0..127
  int qt = blockIdx.x;                // 0..15
  int t = threadIdx.x;
  long base = (long)bh * (S_ * 64);   // 32768
  int mb = bh & 15;                   // mask batch = bh % 16 (faithful tile())

  for (int j = t; j < S_; j += 256)
    smask[j] = (x[mb * S_ + j] == 0) ? 1.0f : 0.0f;

  { // load Q tile (rows qt*32..qt*32+32), contiguous 2048 floats
    const float* qp = q + base + (long)qt * 32 * 64;
    float4 v0 = ((const float4*)qp)[t * 2];
    float4 v1 = ((const float4*)qp)[t * 2 + 1];
    int r = t >> 3, d0 = (t & 7) * 8;
    Qs[r][d0 + 0] = v0.x; Qs[r][d0 + 1] = v0.y; Qs[r][d0 + 2] = v0.z; Qs[r][d0 + 3] = v0.w;
    Qs[r][d0 + 4] = v1.x; Qs[r][d0 + 5] = v1.y; Qs[r][d0 + 6] = v1.z; Qs[r][d0 + 7] = v1.w;
  }

  int rp = t >> 4;     // 0..15 -> rows {rp, rp+16}
  int jg = t & 15;     // 0..15 -> 4 cols / 4 dims

  // ---- logits: S[32][512] over 8 chunks of 64 k-rows
  for (int c = 0; c < 8; c++) {
    __syncthreads();                       // prev chunk done reading Ks
    const float* kp = k + base + (long)c * 64 * 64;
#pragma unroll
    for (int i = 0; i < 16; i++) {
      int idx = t + 256 * i;
      Ks[idx >> 6][idx & 63] = kp[idx];
    }
    __syncthreads();
    float a00 = 0, a01 = 0, a02 = 0, a03 = 0, a10 = 0, a11 = 0, a12 = 0, a13 = 0;
#pragma unroll 8
    for (int d = 0; d < 64; d++) {
      float q0 = Qs[rp][d], q1 = Qs[rp + 16][d];
      float k0 = Ks[jg * 4 + 0][d];
      float k1 = Ks[jg * 4 + 1][d];
      float k2 = Ks[jg * 4 + 2][d];
      float k3 = Ks[jg * 4 + 3][d];
      a00 = fmaf(q0, k0, a00); a01 = fmaf(q0, k1, a01);
      a02 = fmaf(q0, k2, a02); a03 = fmaf(q0, k3, a03);
      a10 = fmaf(q1, k0, a10); a11 = fmaf(q1, k1, a11);
      a12 = fmaf(q1, k2, a12); a13 = fmaf(q1, k3, a13);
    }
    int col = c * 64 + jg * 4;
    float acc0[4] = {a00, a01, a02, a03};
    float acc1[4] = {a10, a11, a12, a13};
#pragma unroll
    for (int cc = 0; cc < 4; cc++) {
      bool m = smask[col + cc] != 0.0f;
      Sb[rp][col + cc]      = m ? -1e9f : acc0[cc] * 0.125f;  // exact -1e9 like ref
      Sb[rp + 16][col + cc] = m ? -1e9f : acc1[cc] * 0.125f;
    }
  }
  __syncthreads();

  // ---- softmax per row (8 lanes per row)
  {
    int r = t >> 3, p = t & 7;
    float m = -1e30f;
    for (int j = p; j < 512; j += 8) m = fmaxf(m, Sb[r][j]);
#pragma unroll
    for (int off = 1; off < 8; off <<= 1) m = fmaxf(m, __shfl_xor(m, off));
    float sum = 0.0f;
    for (int j = p; j < 512; j += 8) {
      float e = __expf(Sb[r][j] - m);
      Sb[r][j] = e;
      sum += e;
    }
#pragma unroll
    for (int off = 1; off < 8; off <<= 1) sum += __shfl_xor(sum, off);
    if (p == 0) rowsum[r] = sum;
  }

  // ---- PV: ctx[32][64] += P_chunk @ V_chunk
  float o00 = 0, o01 = 0, o02 = 0, o03 = 0, o10 = 0, o11 = 0, o12 = 0, o13 = 0;
  for (int c = 0; c < 8; c++) {
    __syncthreads();                       // Vs reuse guard (also covers softmax)
    const float* vp = v + base + (long)c * 64 * 64;
#pragma unroll
    for (int i = 0; i < 16; i++) {
      int idx = t + 256 * i;
      Vs[idx >> 6][idx & 63] = vp[idx];
    }
    __syncthreads();
#pragma unroll 8
    for (int j = 0; j < 64; j++) {
      float p0 = Sb[rp][c * 64 + j];
      float p1 = Sb[rp + 16][c * 64 + j];
      float4 vv = *(const float4*)&Vs[j][jg * 4];
      o00 = fmaf(p0, vv.x, o00); o01 = fmaf(p0, vv.y, o01);
      o02 = fmaf(p0, vv.z, o02); o03 = fmaf(p0, vv.w, o03);
      o10 = fmaf(p1, vv.x, o10); o11 = fmaf(p1, vv.y, o11);
      o12 = fmaf(p1, vv.z, o12); o13 = fmaf(p1, vv.w, o13);
    }
  }
  float inv0 = 1.0f / rowsum[rp];
  float inv1 = 1.0f / rowsum[rp + 16];
  float* cp = ctx + base + (long)qt * 32 * 64;
  *(float4*)(cp + rp * 64 + jg * 4) =
      make_float4(o00 * inv0, o01 * inv0, o02 * inv0, o03 * inv0);
  *(float4*)(cp + (rp + 16) * 64 + jg * 4) =
      make_float4(o10 * inv1, o11 * inv1, o12 * inv1, o13 * inv1);
}

// ------------------------------------------------------------- LayerNorm(a+r)
__global__ __launch_bounds__(256)
void ln_kernel(const float* __restrict__ a, const float* __restrict__ r,
               const float* __restrict__ g, const float* __restrict__ be,
               float* __restrict__ out) {
  int w = threadIdx.x >> 6, lane = threadIdx.x & 63;
  long row = (long)blockIdx.x * 4 + w;
  long base = row * D_ + lane * 8;
  float4 a0 = *(const float4*)(a + base);
  float4 a1 = *(const float4*)(a + base + 4);
  float4 r0 = *(const float4*)(r + base);
  float4 r1 = *(const float4*)(r + base + 4);
  float xv[8] = {a0.x + r0.x, a0.y + r0.y, a0.z + r0.z, a0.w + r0.w,
                 a1.x + r1.x, a1.y + r1.y, a1.z + r1.z, a1.w + r1.w};
  float s = 0;
#pragma unroll
  for (int e = 0; e < 8; e++) s += xv[e];
#pragma unroll
  for (int off = 1; off < 64; off <<= 1) s += __shfl_xor(s, off);
  float m = s * (1.0f / 512.0f);
  float vs = 0;
#pragma unroll
  for (int e = 0; e < 8; e++) { float d = xv[e] - m; vs += d * d; }
#pragma unroll
  for (int off = 1; off < 64; off <<= 1) vs += __shfl_xor(vs, off);
  float rstd = 1.0f / sqrtf(vs * (1.0f / 512.0f) + 1e-5f);
  int gb = lane * 8;
  float o[8];
#pragma unroll
  for (int e = 0; e < 8; e++) o[e] = (xv[e] - m) * rstd * g[gb + e] + be[gb + e];
  *(float4*)(out + base)     = make_float4(o[0], o[1], o[2], o[3]);
  *(float4*)(out + base + 4) = make_float4(o[4], o[5], o[6], o[7]);
}

// ------------------------------------------------------------- launch
extern "C" void kernel_launch(void* const* d_in, const int* in_sizes, int n_in,
                              void* d_out, int out_size, void* d_ws, size_t ws_size,
                              hipStream_t stream) {
  const int*   x    = (const int*)d_in[0];
  const int*   blen = (const int*)d_in[1];
  const float* emb  = (const float*)d_in[2];
  const float* Wq   = (const float*)d_in[3];
  const float* Wk   = (const float*)d_in[4];
  const float* Wv   = (const float*)d_in[5];
  const float* Wo   = (const float*)d_in[6];
  const float* bo   = (const float*)d_in[7];
  const float* ln1g = (const float*)d_in[8];
  const float* ln1b = (const float*)d_in[9];
  const float* W1   = (const float*)d_in[10];
  const float* b1   = (const float*)d_in[11];
  const float* W2   = (const float*)d_in[12];
  const float* b2   = (const float*)d_in[13];
  const float* ln2g = (const float*)d_in[14];
  const float* ln2b = (const float*)d_in[15];
  float* out = (float*)d_out;

  float* ws = (float*)d_ws;
  const long M4 = 4194304;           // 8192*512
  float* h   = ws;
  float* q   = ws + M4;
  float* kk  = ws + 2 * M4;
  float* vv  = ws + 3 * M4;
  float* ctx = ws + 4 * M4;
  float* mid = q;                    // [8192,2048] aliases q..ctx (dead in FFN)
  float* tmp = ws + 5 * M4;

  embed_pe_kernel<<<MT, 256, 0, stream>>>(x, blen, emb, h);

  dim3 g512(512 / BN, MT / BM);      // (4, 64)
  dim3 g2048(F_ / BN, MT / BM);      // (16, 64)
  dim3 gattn(16, 128);

  for (int l = 0; l < L_; l++) {
    const float* wq = Wq + (long)l * D_ * D_;
    const float* wk = Wk + (long)l * D_ * D_;
    const float* wv = Wv + (long)l * D_ * D_;
    const float* wo = Wo + (long)l * D_ * D_;
    const float* w1 = W1 + (long)l * D_ * F_;
    const float* w2 = W2 + (long)l * F_ * D_;

    gemm_kernel<<<g512, 256, 0, stream>>>(h, wq, nullptr, q, MT, D_, D_, 0);
    gemm_kernel<<<g512, 256, 0, stream>>>(h, wk, nullptr, kk, MT, D_, D_, 0);
    gemm_kernel<<<g512, 256, 0, stream>>>(h, wv, nullptr, vv, MT, D_, D_, 0);
    attn_kernel<<<gattn, 256, 0, stream>>>(q, kk, vv, x, ctx);
    gemm_kernel<<<g512, 256, 0, stream>>>(ctx, wo, bo + (long)l * D_, tmp, MT, D_, D_, 0);
    ln_kernel<<<MT / 4, 256, 0, stream>>>(h, tmp, ln1g + (long)l * D_, ln1b + (long)l * D_, h);
    gemm_kernel<<<g2048, 256, 0, stream>>>(h, w1, b1 + (long)l * F_, mid, MT, F_, D_, 1);
    gemm_kernel<<<g512, 256, 0, stream>>>(mid, w2, b2 + (long)l * D_, tmp, MT, D_, F_, 0);
    ln_kernel<<<MT / 4, 256, 0, stream>>>(h, tmp, ln2g + (long)l * D_, ln2b + (long)l * D_,
                                          (l == L_ - 1) ? out : h);
  }
}

// Round 2
// 3129.738 us; speedup vs baseline: 2.1184x; 2.1184x over previous
//
#include <hip/hip_runtime.h>
#include <hip/hip_bf16.h>
#include <cmath>

#define B_  16
#define S_  512
#define D_  512
#define F_  2048
#define L_  6
#define MT  8192  // B_*S_ rows

typedef __attribute__((ext_vector_type(8))) __bf16 bf16x8;
typedef __attribute__((ext_vector_type(4))) float  f32x4;

__device__ __forceinline__ unsigned short f2bf(float f) {
  return __builtin_bit_cast(unsigned short, __float2bfloat16(f));
}

__device__ __forceinline__ void gload16(const void* g, void* l) {
  __builtin_amdgcn_global_load_lds(
      (const __attribute__((address_space(1))) void*)g,
      (__attribute__((address_space(3))) void*)l, 16, 0, 0);
}

// ------------------------------------------------------------- embed + PE
__global__ void embed_pe_kernel(const int* __restrict__ x,
                                const int* __restrict__ blen,
                                const float* __restrict__ emb,
                                float* __restrict__ h,
                                unsigned short* __restrict__ hbf) {
  int bs = blockIdx.x;
  int b = bs >> 9, s = bs & 511;
  int tok = x[bs];
  bool pe = s < blen[b];
  const float* er = emb + (long)tok * D_;
  long rb = (long)bs * D_;
  for (int d = threadIdx.x; d < D_; d += 256) {
    float e = er[d];
    if (pe) {
      float ex = (2.0f * (float)d) / 512.0f;
      float ang = (float)s / powf(10000.0f, ex);
      e += (d & 1) ? cosf(ang) : sinf(ang);
    }
    h[rb + d] = e;
    hbf[rb + d] = f2bf(e);
  }
}

// --------------------------------------------- weight transpose fp32->bf16
// in: [L][K][N] fp32 (stride inls per l), out: [L][N][K] bf16 (stride outls)
__global__ __launch_bounds__(256)
void wconv_kernel(const float* __restrict__ in, unsigned short* __restrict__ out,
                  int K, int N, long inls, long outls) {
  __shared__ float tile[32][33];
  const float* ip = in + (long)blockIdx.z * inls;
  unsigned short* op = out + (long)blockIdx.z * outls;
  int k0 = blockIdx.y * 32, n0 = blockIdx.x * 32;
  int tx = threadIdx.x & 31, ty = threadIdx.x >> 5;
  for (int i = ty; i < 32; i += 8) tile[i][tx] = ip[(long)(k0 + i) * N + n0 + tx];
  __syncthreads();
  for (int i = ty; i < 32; i += 8) op[(long)(n0 + i) * K + k0 + tx] = f2bf(tile[tx][i]);
}

// ------------------------------------------------------------- bf16 MFMA GEMM
// C[M,N] = A[M,K] @ Bt[N,K]^T. 128x128 tile, BK=32, 4 waves, 4x4 frags/wave.
// LDS linear-written via global_load_lds; 16B-granule XOR swizzle applied by
// pre-swizzling the GLOBAL source column (rule #21) and swizzling ds_read.
__global__ __launch_bounds__(256, 2)
void gemm_bf16(const unsigned short* __restrict__ A,
               const unsigned short* __restrict__ Bt,
               const float* __restrict__ bias,
               float* __restrict__ C, unsigned short* __restrict__ Cbf,
               int M, int N, int K, int relu, int qkv) {
  __shared__ unsigned short Al[128 * 32];
  __shared__ unsigned short Bl[128 * 32];
  int t = threadIdx.x;
  int lane = t & 63, wid = t >> 6;
  int rbase = blockIdx.y * 128, cbase = blockIdx.x * 128;
  int wr = (wid >> 1) * 64, wc = (wid & 1) * 64;

  f32x4 acc[4][4];
#pragma unroll
  for (int i = 0; i < 4; i++)
#pragma unroll
    for (int j = 0; j < 4; j++) acc[i][j] = (f32x4){0.f, 0.f, 0.f, 0.f};

  // staging: thread t handles 16B granule t (rows 0..63) and t+256 (rows 64..127)
  int srow = t >> 2;                               // tile row 0..63
  int sc = (((t & 3) ^ ((t >> 3) & 3)) << 3);      // swizzled source col (elems)
  const unsigned short* Ag  = A  + (long)(rbase + srow) * K + sc;
  const unsigned short* Ag2 = A  + (long)(rbase + 64 + srow) * K + sc;
  const unsigned short* Bg  = Bt + (long)(cbase + srow) * K + sc;
  const unsigned short* Bg2 = Bt + (long)(cbase + 64 + srow) * K + sc;
  unsigned short* Ald  = &Al[t * 8];
  unsigned short* Ald2 = &Al[2048 + t * 8];
  unsigned short* Bld  = &Bl[t * 8];
  unsigned short* Bld2 = &Bl[2048 + t * 8];

  int fr = lane & 15;          // fragment row/col within 16
  int c4 = lane >> 4;          // k-granule 0..3 (k0 = c4*8)

  for (int kt = 0; kt < K; kt += 32) {
    gload16(Ag + kt, Ald);
    gload16(Ag2 + kt, Ald2);
    gload16(Bg + kt, Bld);
    gload16(Bg2 + kt, Bld2);
    __syncthreads();  // vmcnt drain + barrier: staged data visible

    bf16x8 a[4], b[4];
#pragma unroll
    for (int m = 0; m < 4; m++) {
      int R = wr + m * 16 + fr;
      a[m] = *(const bf16x8*)&Al[R * 32 + ((c4 ^ ((R >> 1) & 3)) << 3)];
    }
#pragma unroll
    for (int n = 0; n < 4; n++) {
      int R = wc + n * 16 + fr;
      b[n] = *(const bf16x8*)&Bl[R * 32 + ((c4 ^ ((R >> 1) & 3)) << 3)];
    }
#pragma unroll
    for (int m = 0; m < 4; m++)
#pragma unroll
      for (int n = 0; n < 4; n++)
        acc[m][n] = __builtin_amdgcn_mfma_f32_16x16x32_bf16(a[m], b[n], acc[m][n], 0, 0, 0);
    __syncthreads();  // reads done before next stage overwrites
  }

  // epilogue: C/D layout col=lane&15, row=(lane>>4)*4+j  [m89-verified]
  float* Cp = C;
  long Nout = N;
  int cb = cbase;
  if (qkv) {                       // split fused N=1536 into q/k/v (contiguous)
    Cp = C + (long)(cbase >> 9) * (long)M * 512;
    cb = cbase & 511;
    Nout = 512;
  }
#pragma unroll
  for (int m = 0; m < 4; m++) {
#pragma unroll
    for (int n = 0; n < 4; n++) {
      int col = cb + wc + n * 16 + fr;
      float bv = bias ? bias[col] : 0.0f;
#pragma unroll
      for (int j = 0; j < 4; j++) {
        long row = rbase + wr + m * 16 + (lane >> 4) * 4 + j;
        float v = acc[m][n][j] + bv;
        if (relu) v = fmaxf(v, 0.0f);
        if (C)   Cp[row * Nout + col] = v;
        if (Cbf) Cbf[row * Nout + col] = f2bf(v);
      }
    }
  }
}

// ------------------------------------------------------------- attention (fp32)
__global__ __launch_bounds__(256, 1)
void attn_kernel(const float* __restrict__ q, const float* __restrict__ k,
                 const float* __restrict__ v, const int* __restrict__ x,
                 unsigned short* __restrict__ ctxbf) {
  __shared__ float Qs[32][64];
  __shared__ float Ks[64][65];
  __shared__ float Vs[64][68];
  __shared__ float Sb[32][521];
  __shared__ float rowsum[32];
  __shared__ float smask[512];

  int bh = blockIdx.y;
  int qt = blockIdx.x;
  int t = threadIdx.x;
  long base = (long)bh * (S_ * 64);
  int mb = bh & 15;

  for (int j = t; j < S_; j += 256)
    smask[j] = (x[mb * S_ + j] == 0) ? 1.0f : 0.0f;

  {
    const float* qp = q + base + (long)qt * 32 * 64;
    float4 v0 = ((const float4*)qp)[t * 2];
    float4 v1 = ((const float4*)qp)[t * 2 + 1];
    int r = t >> 3, d0 = (t & 7) * 8;
    Qs[r][d0 + 0] = v0.x; Qs[r][d0 + 1] = v0.y; Qs[r][d0 + 2] = v0.z; Qs[r][d0 + 3] = v0.w;
    Qs[r][d0 + 4] = v1.x; Qs[r][d0 + 5] = v1.y; Qs[r][d0 + 6] = v1.z; Qs[r][d0 + 7] = v1.w;
  }

  int rp = t >> 4;
  int jg = t & 15;

  for (int c = 0; c < 8; c++) {
    __syncthreads();
    const float* kp = k + base + (long)c * 64 * 64;
#pragma unroll
    for (int i = 0; i < 16; i++) {
      int idx = t + 256 * i;
      Ks[idx >> 6][idx & 63] = kp[idx];
    }
    __syncthreads();
    float a00 = 0, a01 = 0, a02 = 0, a03 = 0, a10 = 0, a11 = 0, a12 = 0, a13 = 0;
#pragma unroll 8
    for (int d = 0; d < 64; d++) {
      float q0 = Qs[rp][d], q1 = Qs[rp + 16][d];
      float k0 = Ks[jg * 4 + 0][d];
      float k1 = Ks[jg * 4 + 1][d];
      float k2 = Ks[jg * 4 + 2][d];
      float k3 = Ks[jg * 4 + 3][d];
      a00 = fmaf(q0, k0, a00); a01 = fmaf(q0, k1, a01);
      a02 = fmaf(q0, k2, a02); a03 = fmaf(q0, k3, a03);
      a10 = fmaf(q1, k0, a10); a11 = fmaf(q1, k1, a11);
      a12 = fmaf(q1, k2, a12); a13 = fmaf(q1, k3, a13);
    }
    int col = c * 64 + jg * 4;
    float acc0[4] = {a00, a01, a02, a03};
    float acc1[4] = {a10, a11, a12, a13};
#pragma unroll
    for (int cc = 0; cc < 4; cc++) {
      bool m = smask[col + cc] != 0.0f;
      Sb[rp][col + cc]      = m ? -1e9f : acc0[cc] * 0.125f;
      Sb[rp + 16][col + cc] = m ? -1e9f : acc1[cc] * 0.125f;
    }
  }
  __syncthreads();

  {
    int r = t >> 3, p = t & 7;
    float m = -1e30f;
    for (int j = p; j < 512; j += 8) m = fmaxf(m, Sb[r][j]);
#pragma unroll
    for (int off = 1; off < 8; off <<= 1) m = fmaxf(m, __shfl_xor(m, off));
    float sum = 0.0f;
    for (int j = p; j < 512; j += 8) {
      float e = __expf(Sb[r][j] - m);
      Sb[r][j] = e;
      sum += e;
    }
#pragma unroll
    for (int off = 1; off < 8; off <<= 1) sum += __shfl_xor(sum, off);
    if (p == 0) rowsum[r] = sum;
  }

  float o00 = 0, o01 = 0, o02 = 0, o03 = 0, o10 = 0, o11 = 0, o12 = 0, o13 = 0;
  for (int c = 0; c < 8; c++) {
    __syncthreads();
    const float* vp = v + base + (long)c * 64 * 64;
#pragma unroll
    for (int i = 0; i < 16; i++) {
      int idx = t + 256 * i;
      Vs[idx >> 6][idx & 63] = vp[idx];
    }
    __syncthreads();
#pragma unroll 8
    for (int j = 0; j < 64; j++) {
      float p0 = Sb[rp][c * 64 + j];
      float p1 = Sb[rp + 16][c * 64 + j];
      float4 vv = *(const float4*)&Vs[j][jg * 4];
      o00 = fmaf(p0, vv.x, o00); o01 = fmaf(p0, vv.y, o01);
      o02 = fmaf(p0, vv.z, o02); o03 = fmaf(p0, vv.w, o03);
      o10 = fmaf(p1, vv.x, o10); o11 = fmaf(p1, vv.y, o11);
      o12 = fmaf(p1, vv.z, o12); o13 = fmaf(p1, vv.w, o13);
    }
  }
  float inv0 = 1.0f / rowsum[rp];
  float inv1 = 1.0f / rowsum[rp + 16];
  unsigned short* cp = ctxbf + base + (long)qt * 32 * 64;
  ushort4 u0, u1;
  u0.x = f2bf(o00 * inv0); u0.y = f2bf(o01 * inv0);
  u0.z = f2bf(o02 * inv0); u0.w = f2bf(o03 * inv0);
  u1.x = f2bf(o10 * inv1); u1.y = f2bf(o11 * inv1);
  u1.z = f2bf(o12 * inv1); u1.w = f2bf(o13 * inv1);
  *(ushort4*)(cp + rp * 64 + jg * 4) = u0;
  *(ushort4*)(cp + (rp + 16) * 64 + jg * 4) = u1;
}

// ------------------------------------------------------------- LayerNorm(a+r)
__global__ __launch_bounds__(256)
void ln_kernel(const float* __restrict__ a, const float* __restrict__ r,
               const float* __restrict__ g, const float* __restrict__ be,
               float* __restrict__ out, unsigned short* __restrict__ outbf) {
  int w = threadIdx.x >> 6, lane = threadIdx.x & 63;
  long row = (long)blockIdx.x * 4 + w;
  long base = row * D_ + lane * 8;
  float4 a0 = *(const float4*)(a + base);
  float4 a1 = *(const float4*)(a + base + 4);
  float4 r0 = *(const float4*)(r + base);
  float4 r1 = *(const float4*)(r + base + 4);
  float xv[8] = {a0.x + r0.x, a0.y + r0.y, a0.z + r0.z, a0.w + r0.w,
                 a1.x + r1.x, a1.y + r1.y, a1.z + r1.z, a1.w + r1.w};
  float s = 0;
#pragma unroll
  for (int e = 0; e < 8; e++) s += xv[e];
#pragma unroll
  for (int off = 1; off < 64; off <<= 1) s += __shfl_xor(s, off);
  float m = s * (1.0f / 512.0f);
  float vs = 0;
#pragma unroll
  for (int e = 0; e < 8; e++) { float d = xv[e] - m; vs += d * d; }
#pragma unroll
  for (int off = 1; off < 64; off <<= 1) vs += __shfl_xor(vs, off);
  float rstd = 1.0f / sqrtf(vs * (1.0f / 512.0f) + 1e-5f);
  int gb = lane * 8;
  float o[8];
#pragma unroll
  for (int e = 0; e < 8; e++) o[e] = (xv[e] - m) * rstd * g[gb + e] + be[gb + e];
  *(float4*)(out + base)     = make_float4(o[0], o[1], o[2], o[3]);
  *(float4*)(out + base + 4) = make_float4(o[4], o[5], o[6], o[7]);
  ushort4 u0, u1;
  u0.x = f2bf(o[0]); u0.y = f2bf(o[1]); u0.z = f2bf(o[2]); u0.w = f2bf(o[3]);
  u1.x = f2bf(o[4]); u1.y = f2bf(o[5]); u1.z = f2bf(o[6]); u1.w = f2bf(o[7]);
  *(ushort4*)(outbf + base)     = u0;
  *(ushort4*)(outbf + base + 4) = u1;
}

// ------------------------------------------------------------- launch
extern "C" void kernel_launch(void* const* d_in, const int* in_sizes, int n_in,
                              void* d_out, int out_size, void* d_ws, size_t ws_size,
                              hipStream_t stream) {
  const int*   x    = (const int*)d_in[0];
  const int*   blen = (const int*)d_in[1];
  const float* emb  = (const float*)d_in[2];
  const float* Wq   = (const float*)d_in[3];
  const float* Wk   = (const float*)d_in[4];
  const float* Wv   = (const float*)d_in[5];
  const float* Wo   = (const float*)d_in[6];
  const float* bo   = (const float*)d_in[7];
  const float* ln1g = (const float*)d_in[8];
  const float* ln1b = (const float*)d_in[9];
  const float* W1   = (const float*)d_in[10];
  const float* b1   = (const float*)d_in[11];
  const float* W2   = (const float*)d_in[12];
  const float* b2   = (const float*)d_in[13];
  const float* ln2g = (const float*)d_in[14];
  const float* ln2b = (const float*)d_in[15];
  float* out = (float*)d_out;

  float* ws_f = (float*)d_ws;
  const long M4 = 4194304L;          // 8192*512
  float* h   = ws_f;
  float* q   = ws_f + M4;            // q,k,v contiguous (qkv-fused GEMM output)
  float* kk  = ws_f + 2 * M4;
  float* vv  = ws_f + 3 * M4;
  float* tmp = ws_f + 4 * M4;
  unsigned short* bfb    = (unsigned short*)(ws_f + 5 * M4);
  unsigned short* h_bf   = bfb;                      // 8192*512
  unsigned short* ctx_bf = bfb + M4;                 // 8192*512
  unsigned short* Wqkvt  = bfb + 2 * M4;             // [L][1536][512]
  unsigned short* Wot    = Wqkvt + 6L * 1536 * 512;  // [L][512][512]
  unsigned short* W1t    = Wot   + 6L * 512 * 512;   // [L][2048][512]
  unsigned short* W2t    = W1t   + 6L * 2048 * 512;  // [L][512][2048]
  unsigned short* mid_bf = (unsigned short*)q;       // aliases q,kk (dead in FFN)

  // weight convert+transpose: [K][N] fp32 -> [N][K] bf16
  wconv_kernel<<<dim3(16, 16, 6), 256, 0, stream>>>(Wq, Wqkvt,            512, 512,  262144L, 786432L);
  wconv_kernel<<<dim3(16, 16, 6), 256, 0, stream>>>(Wk, Wqkvt + 262144,   512, 512,  262144L, 786432L);
  wconv_kernel<<<dim3(16, 16, 6), 256, 0, stream>>>(Wv, Wqkvt + 524288,   512, 512,  262144L, 786432L);
  wconv_kernel<<<dim3(16, 16, 6), 256, 0, stream>>>(Wo, Wot,              512, 512,  262144L, 262144L);
  wconv_kernel<<<dim3(64, 16, 6), 256, 0, stream>>>(W1, W1t,              512, 2048, 1048576L, 1048576L);
  wconv_kernel<<<dim3(16, 64, 6), 256, 0, stream>>>(W2, W2t,              2048, 512, 1048576L, 1048576L);

  embed_pe_kernel<<<MT, 256, 0, stream>>>(x, blen, emb, h, h_bf);

  dim3 gqkv(12, 64), g512(4, 64), g2048(16, 64), gattn(16, 128);

  for (int l = 0; l < L_; l++) {
    const unsigned short* wqkv = Wqkvt + (long)l * 1536 * 512;
    const unsigned short* wo   = Wot   + (long)l * 512 * 512;
    const unsigned short* w1   = W1t   + (long)l * 2048 * 512;
    const unsigned short* w2   = W2t   + (long)l * 512 * 2048;

    gemm_bf16<<<gqkv, 256, 0, stream>>>(h_bf, wqkv, nullptr, q, nullptr,
                                        MT, 1536, 512, 0, 1);
    attn_kernel<<<gattn, 256, 0, stream>>>(q, kk, vv, x, ctx_bf);
    gemm_bf16<<<g512, 256, 0, stream>>>(ctx_bf, wo, bo + (long)l * D_, tmp, nullptr,
                                        MT, 512, 512, 0, 0);
    ln_kernel<<<MT / 4, 256, 0, stream>>>(h, tmp, ln1g + (long)l * D_,
                                          ln1b + (long)l * D_, h, h_bf);
    gemm_bf16<<<g2048, 256, 0, stream>>>(h_bf, w1, b1 + (long)l * F_, nullptr, mid_bf,
                                         MT, 2048, 512, 1, 0);
    gemm_bf16<<<g512, 256, 0, stream>>>(mid_bf, w2, b2 + (long)l * D_, tmp, nullptr,
                                        MT, 512, 2048, 0, 0);
    ln_kernel<<<MT / 4, 256, 0, stream>>>(h, tmp, ln2g + (long)l * D_,
                                          ln2b + (long)l * D_,
                                          (l == L_ - 1) ? out : h, h_bf);
  }
}

// Round 3
// 1142.673 us; speedup vs baseline: 5.8022x; 2.7390x over previous
//
#include <hip/hip_runtime.h>
#include <hip/hip_bf16.h>
#include <cmath>

#define B_  16
#define S_  512
#define D_  512
#define F_  2048
#define L_  6
#define MT  8192  // B_*S_ rows

typedef __attribute__((ext_vector_type(8))) __bf16 bf16x8;
typedef __attribute__((ext_vector_type(4))) float  f32x4;

__device__ __forceinline__ unsigned short f2bf(float f) {
  return __builtin_bit_cast(unsigned short, __float2bfloat16(f));
}

__device__ __forceinline__ void gload16(const void* g, void* l) {
  __builtin_amdgcn_global_load_lds(
      (const __attribute__((address_space(1))) void*)g,
      (__attribute__((address_space(3))) void*)l, 16, 0, 0);
}

// ------------------------------------------------------------- embed + PE
__global__ void embed_pe_kernel(const int* __restrict__ x,
                                const int* __restrict__ blen,
                                const float* __restrict__ emb,
                                float* __restrict__ h,
                                unsigned short* __restrict__ hbf) {
  int bs = blockIdx.x;
  int b = bs >> 9, s = bs & 511;
  int tok = x[bs];
  bool pe = s < blen[b];
  const float* er = emb + (long)tok * D_;
  long rb = (long)bs * D_;
  for (int d = threadIdx.x; d < D_; d += 256) {
    float e = er[d];
    if (pe) {
      float ex = (2.0f * (float)d) / 512.0f;
      float ang = (float)s / powf(10000.0f, ex);
      e += (d & 1) ? cosf(ang) : sinf(ang);
    }
    h[rb + d] = e;
    hbf[rb + d] = f2bf(e);
  }
}

// ------------------------------------------------------------- pad-mask bits
// maskw[b][w] bit j = (x[b*512 + w*32 + j] == 0)
__global__ void mask_build_kernel(const int* __restrict__ x,
                                  unsigned int* __restrict__ mw) {
  int t = threadIdx.x;            // 256 threads, 1 block
  int b = t >> 4, wd = t & 15;
  unsigned int m = 0;
  for (int j = 0; j < 32; j++)
    if (x[b * 512 + wd * 32 + j] == 0) m |= (1u << j);
  mw[b * 16 + wd] = m;
}

// --------------------------------------------- weight transpose fp32->bf16
__global__ __launch_bounds__(256)
void wconv_kernel(const float* __restrict__ in, unsigned short* __restrict__ out,
                  int K, int N, long inls, long outls) {
  __shared__ float tile[32][33];
  const float* ip = in + (long)blockIdx.z * inls;
  unsigned short* op = out + (long)blockIdx.z * outls;
  int k0 = blockIdx.y * 32, n0 = blockIdx.x * 32;
  int tx = threadIdx.x & 31, ty = threadIdx.x >> 5;
  for (int i = ty; i < 32; i += 8) tile[i][tx] = ip[(long)(k0 + i) * N + n0 + tx];
  __syncthreads();
  for (int i = ty; i < 32; i += 8) op[(long)(n0 + i) * K + k0 + tx] = f2bf(tile[tx][i]);
}

// ------------------------------------------------------------- bf16 MFMA GEMM
// C[M,N] = A[M,K] @ Bt[N,K]^T. 128x128 tile, BK=32, 4 waves, 4x4 frags/wave.
__global__ __launch_bounds__(256, 2)
void gemm_bf16(const unsigned short* __restrict__ A,
               const unsigned short* __restrict__ Bt,
               const float* __restrict__ bias,
               float* __restrict__ C, unsigned short* __restrict__ Cbf,
               int M, int N, int K, int relu, int qkv) {
  __shared__ unsigned short Al[128 * 32];
  __shared__ unsigned short Bl[128 * 32];
  int t = threadIdx.x;
  int lane = t & 63, wid = t >> 6;
  int rbase = blockIdx.y * 128, cbase = blockIdx.x * 128;
  int wr = (wid >> 1) * 64, wc = (wid & 1) * 64;

  f32x4 acc[4][4];
#pragma unroll
  for (int i = 0; i < 4; i++)
#pragma unroll
    for (int j = 0; j < 4; j++) acc[i][j] = (f32x4){0.f, 0.f, 0.f, 0.f};

  int srow = t >> 2;
  int sc = (((t & 3) ^ ((t >> 3) & 3)) << 3);
  const unsigned short* Ag  = A  + (long)(rbase + srow) * K + sc;
  const unsigned short* Ag2 = A  + (long)(rbase + 64 + srow) * K + sc;
  const unsigned short* Bg  = Bt + (long)(cbase + srow) * K + sc;
  const unsigned short* Bg2 = Bt + (long)(cbase + 64 + srow) * K + sc;
  unsigned short* Ald  = &Al[t * 8];
  unsigned short* Ald2 = &Al[2048 + t * 8];
  unsigned short* Bld  = &Bl[t * 8];
  unsigned short* Bld2 = &Bl[2048 + t * 8];

  int fr = lane & 15;
  int c4 = lane >> 4;

  for (int kt = 0; kt < K; kt += 32) {
    gload16(Ag + kt, Ald);
    gload16(Ag2 + kt, Ald2);
    gload16(Bg + kt, Bld);
    gload16(Bg2 + kt, Bld2);
    __syncthreads();

    bf16x8 a[4], b[4];
#pragma unroll
    for (int m = 0; m < 4; m++) {
      int R = wr + m * 16 + fr;
      a[m] = *(const bf16x8*)&Al[R * 32 + ((c4 ^ ((R >> 1) & 3)) << 3)];
    }
#pragma unroll
    for (int n = 0; n < 4; n++) {
      int R = wc + n * 16 + fr;
      b[n] = *(const bf16x8*)&Bl[R * 32 + ((c4 ^ ((R >> 1) & 3)) << 3)];
    }
#pragma unroll
    for (int m = 0; m < 4; m++)
#pragma unroll
      for (int n = 0; n < 4; n++)
        acc[m][n] = __builtin_amdgcn_mfma_f32_16x16x32_bf16(a[m], b[n], acc[m][n], 0, 0, 0);
    __syncthreads();
  }

  if (qkv) {
    // Cbf = q_bf; k_bf at +4194304; vt_bf at +8388608 (transposed per block)
#pragma unroll
    for (int m = 0; m < 4; m++) {
#pragma unroll
      for (int n = 0; n < 4; n++) {
        int col = cbase + wc + n * 16 + fr;
#pragma unroll
        for (int j = 0; j < 4; j++) {
          long row = rbase + wr + m * 16 + (lane >> 4) * 4 + j;
          unsigned short v = f2bf(acc[m][n][j]);
          if (col < 1024) {
            Cbf[(col < 512 ? 0L : 4194304L - 512L) + row * 512 + col] = v;
          } else {
            int cc = col - 1024;
            Cbf[8388608L + (row >> 6) * 32768 + (long)(cc & 63) * 512 +
                ((row & 63) << 3) + (cc >> 6)] = v;
          }
        }
      }
    }
  } else {
#pragma unroll
    for (int m = 0; m < 4; m++) {
#pragma unroll
      for (int n = 0; n < 4; n++) {
        int col = cbase + wc + n * 16 + fr;
        float bv = bias ? bias[col] : 0.0f;
#pragma unroll
        for (int j = 0; j < 4; j++) {
          long row = rbase + wr + m * 16 + (lane >> 4) * 4 + j;
          float v = acc[m][n][j] + bv;
          if (relu) v = fmaxf(v, 0.0f);
          if (C)   C[row * N + col] = v;
          if (Cbf) Cbf[row * N + col] = f2bf(v);
        }
      }
    }
  }
}

// ------------------------------------------------------------- MFMA attention
// Swapped QK^T: lane holds full 512-k logit row of q = (lane&15).
// Grid (8 qt, 128 bh), 4 waves x 16 q-rows. K/Vt staged via global_load_lds
// with inverse-swizzled source; P redistributed in-register via shfl.
__global__ __launch_bounds__(256, 2)
void attn_mfma(const unsigned short* __restrict__ qbf,
               const unsigned short* __restrict__ kbf,
               const unsigned short* __restrict__ vtbf,
               const unsigned int* __restrict__ maskw,
               unsigned short* __restrict__ ctxbf) {
  __shared__ unsigned short sb[8192];   // 16KB staging tile
  int t = threadIdx.x;
  int lane = t & 63, w = t >> 6;
  int c = lane & 15, h = lane >> 4;
  int bh = blockIdx.y, qt = blockIdx.x;
  long bhb = (long)bh << 15;
  int mb = bh & 15;

  const uint4* mp = (const uint4*)(maskw + mb * 16);
  uint4 m0 = mp[0], m1 = mp[1], m2 = mp[2], m3 = mp[3];
  unsigned int mwa[16] = {m0.x, m0.y, m0.z, m0.w, m1.x, m1.y, m1.z, m1.w,
                          m2.x, m2.y, m2.z, m2.w, m3.x, m3.y, m3.z, m3.w};

  // Q fragments (B-operand): direct global reads, row q = qt*64 + w*16 + c
  const bf16x8* qp = (const bf16x8*)(qbf + bhb + (long)(qt * 64 + w * 16 + c) * 64);
  bf16x8 qf0 = qp[h], qf1 = qp[h + 4];

  f32x4 acc[32];
#pragma unroll
  for (int F = 0; F < 32; F++) acc[F] = (f32x4){0.f, 0.f, 0.f, 0.f};

  // ---- S^T = K @ Q^T over 4 chunks of 128 k-rows
#pragma unroll
  for (int ch = 0; ch < 4; ch++) {
    __syncthreads();
#pragma unroll
    for (int i = 0; i < 4; i++) {
      int idx = t + 256 * i;
      int kr = idx >> 3, g = idx & 7;
      gload16(kbf + bhb + (long)(ch * 128 + kr) * 64 + ((g ^ (kr & 7)) << 3),
              &sb[idx * 8]);
    }
    __syncthreads();
#pragma unroll
    for (int f = 0; f < 8; f++) {
      int R = f * 16 + c;
      int ro = R * 64;
      bf16x8 a0 = *(const bf16x8*)&sb[ro + ((h ^ (R & 7)) << 3)];
      bf16x8 a1 = *(const bf16x8*)&sb[ro + (((h + 4) ^ (R & 7)) << 3)];
      acc[ch * 8 + f] = __builtin_amdgcn_mfma_f32_16x16x32_bf16(a0, qf0, acc[ch * 8 + f], 0, 0, 0);
      acc[ch * 8 + f] = __builtin_amdgcn_mfma_f32_16x16x32_bf16(a1, qf1, acc[ch * 8 + f], 0, 0, 0);
    }
  }

  // ---- mask (exact -1e9) + scale; k = F*16 + h*4 + j
#pragma unroll
  for (int F = 0; F < 32; F++) {
    unsigned int nib = (mwa[F >> 1] >> (((F & 1) << 4) + (h << 2))) & 0xFu;
#pragma unroll
    for (int j = 0; j < 4; j++)
      acc[F][j] = (nib & (1u << j)) ? -1e9f : acc[F][j] * 0.125f;
  }

  // ---- softmax (in-register; combine h-groups via shfl_xor 16,32)
  float mx = -3.0e38f;
#pragma unroll
  for (int F = 0; F < 32; F++)
#pragma unroll
    for (int j = 0; j < 4; j++) mx = fmaxf(mx, acc[F][j]);
  mx = fmaxf(mx, __shfl_xor(mx, 16));
  mx = fmaxf(mx, __shfl_xor(mx, 32));
  float sm = 0.f;
#pragma unroll
  for (int F = 0; F < 32; F++)
#pragma unroll
    for (int j = 0; j < 4; j++) {
      float e = __expf(acc[F][j] - mx);
      acc[F][j] = e;
      sm += e;
    }
  sm += __shfl_xor(sm, 16);
  sm += __shfl_xor(sm, 32);

  // ---- pack P to bf16 pairs
  unsigned int pk[64];
#pragma unroll
  for (int F = 0; F < 32; F++) {
    pk[2 * F]     = (unsigned int)f2bf(acc[F][0]) | ((unsigned int)f2bf(acc[F][1]) << 16);
    pk[2 * F + 1] = (unsigned int)f2bf(acc[F][2]) | ((unsigned int)f2bf(acc[F][3]) << 16);
  }

  float rs0 = 1.0f / __shfl(sm, h * 4 + 0);
  float rs1 = 1.0f / __shfl(sm, h * 4 + 1);
  float rs2 = 1.0f / __shfl(sm, h * 4 + 2);
  float rs3 = 1.0f / __shfl(sm, h * 4 + 3);

  // ---- PV: ctx[16q][64d] per wave
  f32x4 o[4];
#pragma unroll
  for (int n = 0; n < 4; n++) o[n] = (f32x4){0.f, 0.f, 0.f, 0.f};
  int l0 = c | ((lane & 16) << 1);   // c + 32*(h&1)
  int l1 = l0 + 16;
  bool hb = (lane & 32) != 0;        // h>>1

#pragma unroll
  for (int ch = 0; ch < 4; ch++) {
    __syncthreads();
#pragma unroll
    for (int i = 0; i < 4; i++) {
      int idx = t + 256 * i;
      int d = idx >> 4, g = idx & 15;
      gload16(vtbf + bhb + (long)d * 512 + ch * 128 + ((g ^ (d & 15)) << 3),
              &sb[idx * 8]);
    }
    __syncthreads();
#pragma unroll
    for (int sub = 0; sub < 4; sub++) {
      int kt4 = (ch * 4 + sub) * 4;   // = 2*fA
      unsigned int a0 = __shfl((int)pk[kt4],     l0);
      unsigned int a1 = __shfl((int)pk[kt4 + 1], l0);
      unsigned int a2 = __shfl((int)pk[kt4],     l1);
      unsigned int a3 = __shfl((int)pk[kt4 + 1], l1);
      unsigned int b0 = __shfl((int)pk[kt4 + 2], l0);
      unsigned int b1 = __shfl((int)pk[kt4 + 3], l0);
      unsigned int b2 = __shfl((int)pk[kt4 + 2], l1);
      unsigned int b3 = __shfl((int)pk[kt4 + 3], l1);
      uint4 aw;
      aw.x = hb ? b0 : a0; aw.y = hb ? b1 : a1;
      aw.z = hb ? b2 : a2; aw.w = hb ? b3 : a3;
      bf16x8 af = __builtin_bit_cast(bf16x8, aw);
#pragma unroll
      for (int n = 0; n < 4; n++) {
        int dl = n * 16 + c;
        bf16x8 vf = *(const bf16x8*)&sb[dl * 128 + (((sub * 4 + h) ^ (dl & 15)) << 3)];
        o[n] = __builtin_amdgcn_mfma_f32_16x16x32_bf16(af, vf, o[n], 0, 0, 0);
      }
    }
  }

  unsigned short* cp = ctxbf + bhb + (long)(qt * 64 + w * 16) * 64;
#pragma unroll
  for (int n = 0; n < 4; n++) {
    cp[(h * 4 + 0) * 64 + n * 16 + c] = f2bf(o[n][0] * rs0);
    cp[(h * 4 + 1) * 64 + n * 16 + c] = f2bf(o[n][1] * rs1);
    cp[(h * 4 + 2) * 64 + n * 16 + c] = f2bf(o[n][2] * rs2);
    cp[(h * 4 + 3) * 64 + n * 16 + c] = f2bf(o[n][3] * rs3);
  }
}

// ------------------------------------------------------------- LayerNorm(a+r)
__global__ __launch_bounds__(256)
void ln_kernel(const float* __restrict__ a, const float* __restrict__ r,
               const float* __restrict__ g, const float* __restrict__ be,
               float* __restrict__ out, unsigned short* __restrict__ outbf) {
  int w = threadIdx.x >> 6, lane = threadIdx.x & 63;
  long row = (long)blockIdx.x * 4 + w;
  long base = row * D_ + lane * 8;
  float4 a0 = *(const float4*)(a + base);
  float4 a1 = *(const float4*)(a + base + 4);
  float4 r0 = *(const float4*)(r + base);
  float4 r1 = *(const float4*)(r + base + 4);
  float xv[8] = {a0.x + r0.x, a0.y + r0.y, a0.z + r0.z, a0.w + r0.w,
                 a1.x + r1.x, a1.y + r1.y, a1.z + r1.z, a1.w + r1.w};
  float s = 0;
#pragma unroll
  for (int e = 0; e < 8; e++) s += xv[e];
#pragma unroll
  for (int off = 1; off < 64; off <<= 1) s += __shfl_xor(s, off);
  float m = s * (1.0f / 512.0f);
  float vs = 0;
#pragma unroll
  for (int e = 0; e < 8; e++) { float d = xv[e] - m; vs += d * d; }
#pragma unroll
  for (int off = 1; off < 64; off <<= 1) vs += __shfl_xor(vs, off);
  float rstd = 1.0f / sqrtf(vs * (1.0f / 512.0f) + 1e-5f);
  int gb = lane * 8;
  float o[8];
#pragma unroll
  for (int e = 0; e < 8; e++) o[e] = (xv[e] - m) * rstd * g[gb + e] + be[gb + e];
  *(float4*)(out + base)     = make_float4(o[0], o[1], o[2], o[3]);
  *(float4*)(out + base + 4) = make_float4(o[4], o[5], o[6], o[7]);
  ushort4 u0, u1;
  u0.x = f2bf(o[0]); u0.y = f2bf(o[1]); u0.z = f2bf(o[2]); u0.w = f2bf(o[3]);
  u1.x = f2bf(o[4]); u1.y = f2bf(o[5]); u1.z = f2bf(o[6]); u1.w = f2bf(o[7]);
  *(ushort4*)(outbf + base)     = u0;
  *(ushort4*)(outbf + base + 4) = u1;
}

// ------------------------------------------------------------- launch
extern "C" void kernel_launch(void* const* d_in, const int* in_sizes, int n_in,
                              void* d_out, int out_size, void* d_ws, size_t ws_size,
                              hipStream_t stream) {
  const int*   x    = (const int*)d_in[0];
  const int*   blen = (const int*)d_in[1];
  const float* emb  = (const float*)d_in[2];
  const float* Wq   = (const float*)d_in[3];
  const float* Wk   = (const float*)d_in[4];
  const float* Wv   = (const float*)d_in[5];
  const float* Wo   = (const float*)d_in[6];
  const float* bo   = (const float*)d_in[7];
  const float* ln1g = (const float*)d_in[8];
  const float* ln1b = (const float*)d_in[9];
  const float* W1   = (const float*)d_in[10];
  const float* b1   = (const float*)d_in[11];
  const float* W2   = (const float*)d_in[12];
  const float* b2   = (const float*)d_in[13];
  const float* ln2g = (const float*)d_in[14];
  const float* ln2b = (const float*)d_in[15];
  float* out = (float*)d_out;

  float* ws_f = (float*)d_ws;
  const long M4 = 4194304L;
  float* h   = ws_f;                 // 4M f32
  float* tmp = ws_f + M4;            // 4M f32
  unsigned short* U = (unsigned short*)(ws_f + 2 * M4);
  unsigned short* h_bf   = U;                    // 4M
  unsigned short* q_bf   = U + M4;               // 4M (k,vt,ctx follow contiguously)
  unsigned short* k_bf   = U + 2 * M4;
  unsigned short* vt_bf  = U + 3 * M4;
  unsigned short* ctx_bf = U + 4 * M4;
  unsigned short* mid_bf = q_bf;                 // [8192][2048] aliases q..ctx
  unsigned short* Wqkvt  = U + 5 * M4;           // 6*1536*512
  unsigned short* Wot    = Wqkvt + 6L * 1536 * 512;
  unsigned short* W1t    = Wot   + 6L * 512 * 512;
  unsigned short* W2t    = W1t   + 6L * 2048 * 512;
  unsigned int*   maskw  = (unsigned int*)(W2t + 6L * 512 * 2048);

  wconv_kernel<<<dim3(16, 16, 6), 256, 0, stream>>>(Wq, Wqkvt,            512, 512,  262144L, 786432L);
  wconv_kernel<<<dim3(16, 16, 6), 256, 0, stream>>>(Wk, Wqkvt + 262144,   512, 512,  262144L, 786432L);
  wconv_kernel<<<dim3(16, 16, 6), 256, 0, stream>>>(Wv, Wqkvt + 524288,   512, 512,  262144L, 786432L);
  wconv_kernel<<<dim3(16, 16, 6), 256, 0, stream>>>(Wo, Wot,              512, 512,  262144L, 262144L);
  wconv_kernel<<<dim3(64, 16, 6), 256, 0, stream>>>(W1, W1t,              512, 2048, 1048576L, 1048576L);
  wconv_kernel<<<dim3(16, 64, 6), 256, 0, stream>>>(W2, W2t,              2048, 512, 1048576L, 1048576L);
  mask_build_kernel<<<1, 256, 0, stream>>>(x, maskw);
  embed_pe_kernel<<<MT, 256, 0, stream>>>(x, blen, emb, h, h_bf);

  dim3 gqkv(12, 64), g512(4, 64), g2048(16, 64), gattn(8, 128);

  for (int l = 0; l < L_; l++) {
    const unsigned short* wqkv = Wqkvt + (long)l * 1536 * 512;
    const unsigned short* wo   = Wot   + (long)l * 512 * 512;
    const unsigned short* w1   = W1t   + (long)l * 2048 * 512;
    const unsigned short* w2   = W2t   + (long)l * 512 * 2048;

    gemm_bf16<<<gqkv, 256, 0, stream>>>(h_bf, wqkv, nullptr, nullptr, q_bf,
                                        MT, 1536, 512, 0, 1);
    attn_mfma<<<gattn, 256, 0, stream>>>(q_bf, k_bf, vt_bf, maskw, ctx_bf);
    gemm_bf16<<<g512, 256, 0, stream>>>(ctx_bf, wo, bo + (long)l * D_, tmp, nullptr,
                                        MT, 512, 512, 0, 0);
    ln_kernel<<<MT / 4, 256, 0, stream>>>(h, tmp, ln1g + (long)l * D_,
                                          ln1b + (long)l * D_, h, h_bf);
    gemm_bf16<<<g2048, 256, 0, stream>>>(h_bf, w1, b1 + (long)l * F_, nullptr, mid_bf,
                                         MT, 2048, 512, 1, 0);
    gemm_bf16<<<g512, 256, 0, stream>>>(mid_bf, w2, b2 + (long)l * D_, tmp, nullptr,
                                        MT, 512, 2048, 0, 0);
    ln_kernel<<<MT / 4, 256, 0, stream>>>(h, tmp, ln2g + (long)l * D_,
                                          ln2b + (long)l * D_,
                                          (l == L_ - 1) ? out : h, h_bf);
  }
}